// Round 5
// baseline (372.268 us; speedup 1.0000x reference)
//
#include <hip/hip_runtime.h>

#define HIDDEN   128
#define TPB      1024
#define PPT      16    // paths per thread

typedef int   v4i __attribute__((ext_vector_type(4)));
typedef float v4f __attribute__((ext_vector_type(4)));
typedef unsigned short u16;
typedef unsigned int   u32;

static __device__ __forceinline__ u16 f32_to_f16_bits(float x) {
    union { _Float16 h; u16 u; } cv;
    cv.h = (_Float16)x;
    return cv.u;
}

// Kernel 1: f16 projection table in CHUNKED layout:
//   proj_h[(c*3 + l) * chunk_nodes + (node - c*chunk_nodes)] = f16(dot(feat[node], W[l]))
// so each chunk is one contiguous 3*chunk_nodes*2-byte block (straight LDS copy).
// One wave per node (wave-uniform node => uniform early-out is safe).
__global__ __launch_bounds__(256) void proj_kernel(
    const float* __restrict__ feat,   // (n_nodes, 128)
    const float* __restrict__ W,      // (3, 1, 128)
    u16* __restrict__ proj_h,         // nchunks * 3 * chunk_nodes
    int n_nodes, int chunk_nodes)
{
    int gtid = blockIdx.x * blockDim.x + threadIdx.x;
    int node = gtid >> 6;
    int lane = threadIdx.x & 63;
    if (node >= n_nodes) return;

    const float2* f2 = (const float2*)(feat + (size_t)node * HIDDEN);
    const float2* w2 = (const float2*)W;

    float2 f   = f2[lane];
    float2 w0  = w2[lane];           // W[0]
    float2 w1  = w2[64 + lane];      // W[1]
    float2 wv2 = w2[128 + lane];     // W[2]

    float s0 = f.x * w0.x  + f.y * w0.y;
    float s1 = f.x * w1.x  + f.y * w1.y;
    float s2 = f.x * wv2.x + f.y * wv2.y;

    #pragma unroll
    for (int off = 32; off > 0; off >>= 1) {
        s0 += __shfl_xor(s0, off, 64);
        s1 += __shfl_xor(s1, off, 64);
        s2 += __shfl_xor(s2, off, 64);
    }

    if (lane == 0) {
        int c     = node / chunk_nodes;
        int local = node - c * chunk_nodes;
        u16* base = proj_h + (size_t)c * 3 * chunk_nodes + local;
        base[0]                = f32_to_f16_bits(s0);
        base[chunk_nodes]      = f32_to_f16_bits(s1);
        base[2 * chunk_nodes]  = f32_to_f16_bits(s2);
    }
}

// Kernel 2: ids resident in registers; loop over node chunks. Each pass:
// cooperative contiguous copy of the chunk into LDS (conflict-free b128
// writes), barrier, then 48 ds_read_u16 gathers per thread. Out-of-chunk
// or invalid (-1) ids read a zeroed dummy slot (no select chain on the
// accumulate path). This moves 30M divergent lanes off the TA/vector-mem
// pipe (measured ~3 cyc/lane = the 141 us wall) onto the LDS pipe.
__global__ __launch_bounds__(TPB, 4) void score_kernel(
    const int* __restrict__ paths,    // (n_paths, 3) int32
    const u16* __restrict__ proj_h,   // chunked f16 table
    float* __restrict__ out,          // (n_paths,)
    int n_paths, int chunk_nodes, int nchunks)
{
    extern __shared__ u16 lds[];          // 3*chunk_nodes + dummy slot
    const int dummy = 3 * chunk_nodes;

    int t = blockIdx.x * TPB + threadIdx.x;

    // Load 16 paths = 48 ids = 12 int4s (nt: keep L2 for the proj table).
    const int NV = 3 * PPT / 4;
    int n_v4 = (n_paths * 3) >> 2;
    const v4i* p4 = (const v4i*)paths;
    int ids[3 * PPT];
    #pragma unroll
    for (int i = 0; i < NV; ++i) {
        int idx = t * NV + i;
        v4i v;
        if (idx < n_v4) v = __builtin_nontemporal_load(p4 + idx);
        else            v = (v4i){-1, -1, -1, -1};
        ids[4*i+0] = v.x; ids[4*i+1] = v.y; ids[4*i+2] = v.z; ids[4*i+3] = v.w;
    }

    if (threadIdx.x == 0) lds[dummy] = 0;   // fills never touch this slot

    float acc[PPT];
    #pragma unroll
    for (int p = 0; p < PPT; ++p) acc[p] = 0.0f;

    const int vecs = (3 * chunk_nodes) >> 3;   // 16-byte units per chunk
    const v4i* src = (const v4i*)proj_h;
    v4i* dst = (v4i*)lds;

    for (int c = 0; c < nchunks; ++c) {
        __syncthreads();                       // prior pass reads done
        for (int w = threadIdx.x; w < vecs; w += TPB)
            dst[w] = src[(size_t)c * vecs + w];
        __syncthreads();

        int cbase = c * chunk_nodes;
        #pragma unroll
        for (int p = 0; p < PPT; ++p) {
            #pragma unroll
            for (int l = 0; l < 3; ++l) {
                u32 loc = (u32)(ids[3*p + l] - cbase);  // id<0 => huge => dummy
                int off = (loc < (u32)chunk_nodes)
                          ? (l * chunk_nodes + (int)loc) : dummy;
                union { u16 u; _Float16 h; } cv;
                cv.u = lds[off];
                acc[p] += (float)cv.h;
            }
        }
    }

    int out4 = n_paths >> 2;
    #pragma unroll
    for (int j = 0; j < PPT / 4; ++j) {
        int idx = t * (PPT / 4) + j;
        v4f o;
        #pragma unroll
        for (int q = 0; q < 4; ++q) {
            int p = 4*j + q;
            int cnt = (int)(ids[3*p] >= 0) + (int)(ids[3*p+1] >= 0)
                    + (int)(ids[3*p+2] >= 0);
            float inv = (cnt == 3) ? (1.0f/3.0f) : (cnt == 2 ? 0.5f : 1.0f);
            o[q] = acc[p] * inv;
        }
        if (idx < out4)
            __builtin_nontemporal_store(o, ((v4f*)out) + idx);
    }
}

extern "C" void kernel_launch(void* const* d_in, const int* in_sizes, int n_in,
                              void* d_out, int out_size, void* d_ws, size_t ws_size,
                              hipStream_t stream) {
    const int*   paths = (const int*)d_in[0];     // (N_PATHS, 3) int32
    const float* feat  = (const float*)d_in[1];   // (N_NODES, 128) f32
    const float* W     = (const float*)d_in[2];   // (3, 1, 128) f32
    float*       out   = (float*)d_out;           // (N_PATHS,) f32

    int n_nodes = in_sizes[1] / HIDDEN;           // 100000
    int n_paths = in_sizes[0] / 3;                // 10000000
    u16* proj_h = (u16*)d_ws;                     // <= ~0.65 MB

    // Prefer 25,600-node chunks (150 KB LDS, 4 passes). Fall back to
    // 10,880-node chunks (63.8 KB, 10 passes) if the device can't hold it.
    int chunk_nodes = 25600;
    int dev = 0;
    (void)hipGetDevice(&dev);
    int max_lds = 0;
    (void)hipDeviceGetAttribute(&max_lds,
            hipDeviceAttributeMaxSharedMemoryPerMultiprocessor, dev);
    size_t lds_bytes = (size_t)3 * chunk_nodes * sizeof(u16) + 4;
    if (max_lds > 0 && (size_t)max_lds < lds_bytes)
        chunk_nodes = 10880;                       // known-safe <64 KB
    lds_bytes = (size_t)3 * chunk_nodes * sizeof(u16) + 4;
    // Opt-in for >48/64 KB dynamic LDS; harmless if already allowed.
    (void)hipFuncSetAttribute((const void*)score_kernel,
            hipFuncAttributeMaxDynamicSharedMemorySize, (int)lds_bytes);
    (void)hipGetLastError();                       // clear any sticky error

    int nchunks = (n_nodes + chunk_nodes - 1) / chunk_nodes;

    // Kernel 1: 1 wave per node, 4 waves per 256-thread block.
    {
        int blocks = (n_nodes + 3) / 4;
        proj_kernel<<<blocks, 256, 0, stream>>>(feat, W, proj_h,
                                                n_nodes, chunk_nodes);
    }

    // Kernel 2: 16 paths per thread, 1024-thread blocks, chunked LDS table.
    {
        int nthreads = (n_paths + PPT - 1) / PPT;  // 625,000
        int blocks = (nthreads + TPB - 1) / TPB;   // 611
        score_kernel<<<blocks, TPB, lds_bytes, stream>>>(paths, proj_h, out,
                                                         n_paths, chunk_nodes,
                                                         nchunks);
    }
}

// Round 6
// 297.784 us; speedup vs baseline: 1.2501x; 1.2501x over previous
//
#include <hip/hip_runtime.h>

#define HIDDEN       128
#define TPB          1024
#define PPT          8          // paths per thread (24 ids + 8 acc: no spill)
#define CHUNK_NODES  25600      // 3 * 25600 * 2 B = 150 KB LDS chunk

typedef int   v4i __attribute__((ext_vector_type(4)));
typedef float v4f __attribute__((ext_vector_type(4)));
typedef unsigned short u16;
typedef unsigned int   u32;

static __device__ __forceinline__ u16 f32_to_f16_bits(float x) {
    union { _Float16 h; u16 u; } cv;
    cv.h = (_Float16)x;
    return cv.u;
}

// Kernel 1: f16 projection table in CHUNKED layout. Chunk c is a contiguous
// 150 KB block: [l=0 plane | l=1 plane | l=2 plane], each CHUNK_NODES u16s.
// One wave per node.
__global__ __launch_bounds__(256) void proj_kernel(
    const float* __restrict__ feat,   // (n_nodes, 128)
    const float* __restrict__ W,      // (3, 1, 128)
    u16* __restrict__ proj_h,         // nchunks * 3 * CHUNK_NODES
    int n_nodes)
{
    int gtid = blockIdx.x * blockDim.x + threadIdx.x;
    int node = gtid >> 6;
    int lane = threadIdx.x & 63;
    if (node >= n_nodes) return;

    const float2* f2 = (const float2*)(feat + (size_t)node * HIDDEN);
    const float2* w2 = (const float2*)W;

    float2 f   = f2[lane];
    float2 w0  = w2[lane];           // W[0]
    float2 w1  = w2[64 + lane];      // W[1]
    float2 wv2 = w2[128 + lane];     // W[2]

    float s0 = f.x * w0.x  + f.y * w0.y;
    float s1 = f.x * w1.x  + f.y * w1.y;
    float s2 = f.x * wv2.x + f.y * wv2.y;

    #pragma unroll
    for (int off = 32; off > 0; off >>= 1) {
        s0 += __shfl_xor(s0, off, 64);
        s1 += __shfl_xor(s1, off, 64);
        s2 += __shfl_xor(s2, off, 64);
    }

    if (lane == 0) {
        int c     = node / CHUNK_NODES;
        int local = node - c * CHUNK_NODES;
        u16* base = proj_h + (size_t)c * 3 * CHUNK_NODES + local;
        base[0]               = f32_to_f16_bits(s0);
        base[CHUNK_NODES]     = f32_to_f16_bits(s1);
        base[2 * CHUNK_NODES] = f32_to_f16_bits(s2);
    }
}

// Kernel 2: 8 paths/thread resident in registers; 4 chunk passes. Per pass:
// cooperative contiguous 150 KB fill (conflict-free b128), barrier, then
// 24 ds_read_u16 gathers per thread (out-of-chunk / -1 ids hit a zeroed
// dummy slot). No early return (all threads reach barriers); no branch in
// the id-load loop (clamped index) so SROA keeps arrays in VGPRs.
__global__ __launch_bounds__(TPB, 4) void score_kernel(
    const int* __restrict__ paths,    // (n_paths, 3) int32
    const u16* __restrict__ proj_h,   // chunked f16 table
    float* __restrict__ out,          // (n_paths,)
    int n_threads, int nchunks)
{
    extern __shared__ u16 lds[];              // 3*CHUNK_NODES u16 + dummy
    const int dummy = 3 * CHUNK_NODES;        // u16 index of zero slot

    int t  = blockIdx.x * TPB + threadIdx.x;
    int tl = t < n_threads ? t : n_threads - 1;   // clamp, no divergence in loads

    // 8 paths = 24 ids = 6 int4 loads (consume each int4 immediately).
    int ids[3 * PPT];
    const v4i* p4 = (const v4i*)paths;
    #pragma unroll
    for (int i = 0; i < 6; ++i) {
        v4i v = __builtin_nontemporal_load(p4 + (size_t)tl * 6 + i);
        ids[4*i+0] = v.x; ids[4*i+1] = v.y; ids[4*i+2] = v.z; ids[4*i+3] = v.w;
    }

    if (threadIdx.x == 0) lds[dummy] = 0;

    float acc[PPT];
    #pragma unroll
    for (int p = 0; p < PPT; ++p) acc[p] = 0.0f;

    const v4i* src  = (const v4i*)proj_h;
    v4i*       dst  = (v4i*)lds;
    const int  vecs = 3 * CHUNK_NODES / 8;    // 16-byte units per chunk = 9600

    for (int c = 0; c < nchunks; ++c) {
        __syncthreads();                      // prior pass's reads done
        for (int w = threadIdx.x; w < vecs; w += TPB)
            dst[w] = src[(size_t)c * vecs + w];
        __syncthreads();

        int cbase = c * CHUNK_NODES;
        #pragma unroll
        for (int p = 0; p < PPT; ++p) {
            #pragma unroll
            for (int l = 0; l < 3; ++l) {
                u32 loc = (u32)(ids[3*p + l] - cbase);   // id<0 => huge => dummy
                int off = (loc < (u32)CHUNK_NODES)
                          ? (l * CHUNK_NODES + (int)loc) : dummy;
                union { u16 u; _Float16 h; } cv;
                cv.u = lds[off];
                acc[p] += (float)cv.h;
            }
        }
    }

    if (t < n_threads) {
        #pragma unroll
        for (int j = 0; j < PPT / 4; ++j) {
            v4f o;
            #pragma unroll
            for (int q = 0; q < 4; ++q) {
                int p = 4*j + q;
                int cnt = (int)(ids[3*p] >= 0) + (int)(ids[3*p+1] >= 0)
                        + (int)(ids[3*p+2] >= 0);
                float inv = (cnt == 3) ? (1.0f/3.0f) : (cnt == 2 ? 0.5f : 1.0f);
                o[q] = acc[p] * inv;
            }
            __builtin_nontemporal_store(o, ((v4f*)out) + (size_t)t * 2 + j);
        }
    }
}

extern "C" void kernel_launch(void* const* d_in, const int* in_sizes, int n_in,
                              void* d_out, int out_size, void* d_ws, size_t ws_size,
                              hipStream_t stream) {
    const int*   paths = (const int*)d_in[0];     // (N_PATHS, 3) int32
    const float* feat  = (const float*)d_in[1];   // (N_NODES, 128) f32
    const float* W     = (const float*)d_in[2];   // (3, 1, 128) f32
    float*       out   = (float*)d_out;           // (N_PATHS,) f32

    int n_nodes = in_sizes[1] / HIDDEN;           // 100000
    int n_paths = in_sizes[0] / 3;                // 10000000
    u16* proj_h = (u16*)d_ws;                     // padded: nchunks*150 KB

    int nchunks = (n_nodes + CHUNK_NODES - 1) / CHUNK_NODES;   // 4
    size_t lds_bytes = (size_t)3 * CHUNK_NODES * sizeof(u16) + 4;  // 153604

    (void)hipFuncSetAttribute((const void*)score_kernel,
            hipFuncAttributeMaxDynamicSharedMemorySize, (int)lds_bytes);
    (void)hipGetLastError();   // clear any sticky error pre-capture

    // Kernel 1: 1 wave per node, 4 waves per 256-thread block.
    {
        int blocks = (n_nodes + 3) / 4;
        proj_kernel<<<blocks, 256, 0, stream>>>(feat, W, proj_h, n_nodes);
    }

    // Kernel 2: 8 paths/thread, 1024-thread blocks, 4 LDS chunk passes.
    {
        int n_threads = (n_paths + PPT - 1) / PPT;     // 1,250,000
        int blocks = (n_threads + TPB - 1) / TPB;      // 1221
        score_kernel<<<blocks, TPB, lds_bytes, stream>>>(paths, proj_h, out,
                                                         n_threads, nchunks);
    }
}

// Round 7
// 285.683 us; speedup vs baseline: 1.3031x; 1.0424x over previous
//
#include <hip/hip_runtime.h>

#define HIDDEN       128
#define TPB          1024
#define PPT          8          // paths per thread (24 ids + 8 acc: no spill)
#define CHUNK_NODES  25600      // 3 * 25600 * 2 B = 150 KB LDS chunk
#define CHUNK_BYTES  (3 * CHUNK_NODES * 2)   // 153600
#define FILL_UNITS   (CHUNK_BYTES / 1024)    // 150 x 1KB wave-units

typedef int   v4i __attribute__((ext_vector_type(4)));
typedef float v4f __attribute__((ext_vector_type(4)));
typedef unsigned short u16;
typedef unsigned int   u32;

static __device__ __forceinline__ u16 f32_to_f16_bits(float x) {
    union { _Float16 h; u16 u; } cv;
    cv.h = (_Float16)x;
    return cv.u;
}

// Async global->LDS DMA, 16 B per lane: lane i's 16 B from its own global
// address land at (wave-uniform lds base) + i*16.
static __device__ __forceinline__ void gload_lds16(const void* gp, void* lp) {
    __builtin_amdgcn_global_load_lds(
        (const __attribute__((address_space(1))) unsigned int*)gp,
        (__attribute__((address_space(3))) unsigned int*)lp,
        16, 0, 0);
}

// Kernel 1: f16 projection table in CHUNKED layout. Chunk c is a contiguous
// 150 KB block: [l=0 plane | l=1 plane | l=2 plane], each CHUNK_NODES u16s.
// One wave per node.
__global__ __launch_bounds__(256) void proj_kernel(
    const float* __restrict__ feat,   // (n_nodes, 128)
    const float* __restrict__ W,      // (3, 1, 128)
    u16* __restrict__ proj_h,         // nchunks * 3 * CHUNK_NODES
    int n_nodes)
{
    int gtid = blockIdx.x * blockDim.x + threadIdx.x;
    int node = gtid >> 6;
    int lane = threadIdx.x & 63;
    if (node >= n_nodes) return;

    const float2* f2 = (const float2*)(feat + (size_t)node * HIDDEN);
    const float2* w2 = (const float2*)W;

    float2 f   = f2[lane];
    float2 w0  = w2[lane];           // W[0]
    float2 w1  = w2[64 + lane];      // W[1]
    float2 wv2 = w2[128 + lane];     // W[2]

    float s0 = f.x * w0.x  + f.y * w0.y;
    float s1 = f.x * w1.x  + f.y * w1.y;
    float s2 = f.x * wv2.x + f.y * wv2.y;

    #pragma unroll
    for (int off = 32; off > 0; off >>= 1) {
        s0 += __shfl_xor(s0, off, 64);
        s1 += __shfl_xor(s1, off, 64);
        s2 += __shfl_xor(s2, off, 64);
    }

    if (lane == 0) {
        int c     = node / CHUNK_NODES;
        int local = node - c * CHUNK_NODES;
        u16* base = proj_h + (size_t)c * 3 * CHUNK_NODES + local;
        base[0]               = f32_to_f16_bits(s0);
        base[CHUNK_NODES]     = f32_to_f16_bits(s1);
        base[2 * CHUNK_NODES] = f32_to_f16_bits(s2);
    }
}

// Kernel 2: 8 paths/thread in registers; 4 chunk passes. Fill is ASYNC
// global_load_lds (no VGPR round-trip, no per-iteration waits — the
// __syncthreads drain is the only wait). Gathers: 24 ds_read_u16/thread/
// pass; out-of-chunk / -1 ids hit a zeroed dummy slot. Grid is padded to
// an exact multiple of 256 blocks (uniform 5 blocks/CU, no tail imbalance);
// overrun threads clamp loads, skip stores, and run all barriers.
__global__ __launch_bounds__(TPB, 4) void score_kernel(
    const int* __restrict__ paths,    // (n_paths, 3) int32
    const u16* __restrict__ proj_h,   // chunked f16 table
    float* __restrict__ out,          // (n_paths,)
    int n_threads, int nchunks)
{
    extern __shared__ u16 lds[];              // 3*CHUNK_NODES u16 + dummy
    const int dummy = 3 * CHUNK_NODES;        // u16 index of zero slot

    int t    = blockIdx.x * TPB + threadIdx.x;
    int tl   = t < n_threads ? t : n_threads - 1;  // clamp: uniform control flow
    int wid  = threadIdx.x >> 6;
    int lane = threadIdx.x & 63;

    // 8 paths = 24 ids = 6 int4 loads (consume each int4 immediately).
    int ids[3 * PPT];
    const v4i* p4 = (const v4i*)paths;
    #pragma unroll
    for (int i = 0; i < 6; ++i) {
        v4i v = __builtin_nontemporal_load(p4 + (size_t)tl * 6 + i);
        ids[4*i+0] = v.x; ids[4*i+1] = v.y; ids[4*i+2] = v.z; ids[4*i+3] = v.w;
    }

    if (threadIdx.x == 0) lds[dummy] = 0;     // visible after first barrier

    float acc[PPT];
    #pragma unroll
    for (int p = 0; p < PPT; ++p) acc[p] = 0.0f;

    const unsigned char* src  = (const unsigned char*)proj_h;
    char*                ldsb = (char*)lds;

    for (int c = 0; c < nchunks; ++c) {
        // Async fill: each wave DMAs its 1 KB units back-to-back, zero waits.
        const unsigned char* gsrc = src + (size_t)c * CHUNK_BYTES;
        for (int j = wid; j < FILL_UNITS; j += TPB / 64)
            gload_lds16(gsrc + j * 1024 + lane * 16, ldsb + j * 1024);
        __syncthreads();                      // drains vmcnt: fill complete

        int cbase = c * CHUNK_NODES;
        #pragma unroll
        for (int p = 0; p < PPT; ++p) {
            #pragma unroll
            for (int l = 0; l < 3; ++l) {
                u32 loc = (u32)(ids[3*p + l] - cbase);   // id<0 => huge => dummy
                int off = (loc < (u32)CHUNK_NODES)
                          ? (l * CHUNK_NODES + (int)loc) : dummy;
                union { u16 u; _Float16 h; } cv;
                cv.u = lds[off];
                acc[p] += (float)cv.h;
            }
        }
        if (c + 1 < nchunks) __syncthreads(); // reads done before next fill
    }

    if (t < n_threads) {
        #pragma unroll
        for (int j = 0; j < PPT / 4; ++j) {
            v4f o;
            #pragma unroll
            for (int q = 0; q < 4; ++q) {
                int p = 4*j + q;
                int cnt = (int)(ids[3*p] >= 0) + (int)(ids[3*p+1] >= 0)
                        + (int)(ids[3*p+2] >= 0);
                float inv = (cnt == 3) ? (1.0f/3.0f) : (cnt == 2 ? 0.5f : 1.0f);
                o[q] = acc[p] * inv;
            }
            __builtin_nontemporal_store(o, ((v4f*)out) + (size_t)t * 2 + j);
        }
    }
}

extern "C" void kernel_launch(void* const* d_in, const int* in_sizes, int n_in,
                              void* d_out, int out_size, void* d_ws, size_t ws_size,
                              hipStream_t stream) {
    const int*   paths = (const int*)d_in[0];     // (N_PATHS, 3) int32
    const float* feat  = (const float*)d_in[1];   // (N_NODES, 128) f32
    const float* W     = (const float*)d_in[2];   // (3, 1, 128) f32
    float*       out   = (float*)d_out;           // (N_PATHS,) f32

    int n_nodes = in_sizes[1] / HIDDEN;           // 100000
    int n_paths = in_sizes[0] / 3;                // 10000000
    u16* proj_h = (u16*)d_ws;                     // nchunks * 150 KB = 600 KB

    int nchunks = (n_nodes + CHUNK_NODES - 1) / CHUNK_NODES;       // 4
    size_t lds_bytes = (size_t)3 * CHUNK_NODES * sizeof(u16) + 4;  // 153604

    (void)hipFuncSetAttribute((const void*)score_kernel,
            hipFuncAttributeMaxDynamicSharedMemorySize, (int)lds_bytes);
    (void)hipGetLastError();   // clear any sticky error pre-capture

    // Kernel 1: 1 wave per node, 4 waves per 256-thread block.
    {
        int blocks = (n_nodes + 3) / 4;
        proj_kernel<<<blocks, 256, 0, stream>>>(feat, W, proj_h, n_nodes);
    }

    // Kernel 2: grid padded to a multiple of 256 blocks (exactly 5/CU).
    {
        int n_threads = (n_paths + PPT - 1) / PPT;     // 1,250,000
        int blocks = (n_threads + TPB - 1) / TPB;      // 1221
        blocks = ((blocks + 255) / 256) * 256;         // 1280 = 5 * 256
        score_kernel<<<blocks, TPB, lds_bytes, stream>>>(paths, proj_h, out,
                                                         n_threads, nchunks);
    }
}